// Round 6
// baseline (428.237 us; speedup 1.0000x reference)
//
#include <hip/hip_runtime.h>
#include <math.h>

// Problem constants
#define B_    8
#define E_    512
#define L_    8192
#define K_    5
#define LC    8188      // L - K + 1
#define LOUT  4096      // L / DS
#define XROWS 8200      // xT t-rows: 8192 data + 8 slack rows
#define LCP   8208      // padded y/z row length: [0,8) front zeros, data at 8+t, back zeros

// conv pipeline geometry (K-step = 16 i, ping-pong LDS, counted vmcnt)
#define XR      516     // staged t-rows per block (512 + K-1)
#define PITCH   24      // ushorts per LDS row (48 B: 2x16B data + 16B pad)
#define XCH     1548    // X chunks of 16 B per step (516*3)
#define WCH     960     // W chunks (320*3)
#define NCH     2508    // total chunks/step
#define CPW     627     // chunks per wave (NCH/4)
#define BUFU    20064   // ushorts per buffer (NCH*8)
#define WOFF    12384   // W region offset in buffer (XCH*8)

typedef float  f32x4   __attribute__((ext_vector_type(4)));
typedef float  f32x16  __attribute__((ext_vector_type(16)));
typedef short  s16x4   __attribute__((ext_vector_type(4)));
typedef short  s16x8   __attribute__((ext_vector_type(8)));

__device__ __forceinline__ unsigned short f2bf(float f) {
    union { float f; unsigned u; } v; v.f = f;
    unsigned r = v.u + 0x7FFFu + ((v.u >> 16) & 1u);
    return (unsigned short)(r >> 16);
}
__device__ __forceinline__ float bflo(unsigned u) {
    union { unsigned u; float f; } v; v.u = u << 16; return v.f;
}
__device__ __forceinline__ float bfhi(unsigned u) {
    union { unsigned u; float f; } v; v.u = u & 0xFFFF0000u; return v.f;
}

__device__ __forceinline__ void gload16(const unsigned short* g, unsigned short* l) {
    __builtin_amdgcn_global_load_lds(
        (const __attribute__((address_space(1))) unsigned int*)g,
        (__attribute__((address_space(3))) unsigned int*)l, 16, 0, 0);
}

// ---------------------------------------------------------------------------
// Kernel 0: pack conv weight [e][i][k] fp32 -> Wtb[k][e][i] bf16
// ---------------------------------------------------------------------------
__global__ __launch_bounds__(256) void wt_kernel(const float* __restrict__ w,
                                                 unsigned short* __restrict__ Wtb) {
    int idx = blockIdx.x * 256 + threadIdx.x;
    if (idx >= E_ * E_ * K_) return;
    int i    = idx & (E_ - 1);
    int rest = idx >> 9;            // k*E + e
    int e    = rest & (E_ - 1);
    int k    = rest >> 9;
    Wtb[idx] = f2bf(w[((size_t)e * E_ + i) * K_ + k]);
}

// ---------------------------------------------------------------------------
// Kernel 1: transpose x[b][i][t] fp32 -> xT[b][t][i] bf16 (f32x4 loads)
// ---------------------------------------------------------------------------
__global__ __launch_bounds__(256) void xt_kernel(const float* __restrict__ x,
                                                 unsigned short* __restrict__ xT) {
    __shared__ float s[64][65];
    const int b  = blockIdx.z;
    const int i0 = blockIdx.y * 64;
    const int t0 = blockIdx.x * 64;
    #pragma unroll
    for (int j = 0; j < 4; ++j) {
        int idx = threadIdx.x + j * 256;
        int r = idx >> 4, c4 = idx & 15;
        f32x4 v = *(const f32x4*)(x + ((size_t)b * E_ + i0 + r) * L_ + t0 + c4 * 4);
        s[c4 * 4 + 0][r] = v[0];
        s[c4 * 4 + 1][r] = v[1];
        s[c4 * 4 + 2][r] = v[2];
        s[c4 * 4 + 3][r] = v[3];
    }
    __syncthreads();
    #pragma unroll
    for (int j = 0; j < 4; ++j) {
        int idx = threadIdx.x + j * 256;
        int tt = idx >> 4, ig = (idx & 15) * 4;
        s16x4 v;
        v[0] = (short)f2bf(s[tt][ig + 0]);
        v[1] = (short)f2bf(s[tt][ig + 1]);
        v[2] = (short)f2bf(s[tt][ig + 2]);
        v[3] = (short)f2bf(s[tt][ig + 3]);
        *(s16x4*)&xT[((size_t)b * XROWS + t0 + tt) * E_ + i0 + ig] = v;
    }
}

// ---------------------------------------------------------------------------
// Kernel 2: zero zP[B][LCP] fully + yP edge pads
// ---------------------------------------------------------------------------
__global__ __launch_bounds__(256) void zero_aux(unsigned short* __restrict__ yP,
                                                float* __restrict__ zP) {
    int idx = blockIdx.x * 256 + threadIdx.x;
    if (idx < B_ * LCP) zP[idx] = 0.f;
    int i2 = idx - B_ * LCP;
    if (i2 >= 0 && i2 < B_ * E_ * 20) {
        int row = i2 / 20, j = i2 - row * 20;
        int col = (j < 8) ? j : (8 + LC + (j - 8));
        yP[(size_t)row * LCP + col] = 0;
    }
}

// ---------------------------------------------------------------------------
// Kernel 3: implicit-GEMM conv, 32x32x16 bf16 MFMA + fused z-score.
// NEW schedule (T3+T4): K-step 16 i, ping-pong LDS buffers filled by
// global_load_lds DMA, counted s_waitcnt vmcnt(10) (never 0 in main loop),
// raw s_barrier. Fragment math & epilogue identical to the proven round-3.
// ---------------------------------------------------------------------------
__global__ __launch_bounds__(256, 2) void conv_mfma(const unsigned short* __restrict__ xT,
                                                    const unsigned short* __restrict__ Wtb,
                                                    const float* __restrict__ bias,
                                                    const float* __restrict__ sw,
                                                    unsigned short* __restrict__ yP,
                                                    float* __restrict__ zP) {
    __shared__ unsigned short SB[2][BUFU];   // [X 516 rows x 24u | W 320 rows x 24u]
    __shared__ float swb[128];               // [0:64) = score_w, [64:128) = bias

    const int tid  = threadIdx.x;
    const int nt   = blockIdx.x;
    const int b    = nt >> 4;
    const int tb   = (nt & 15) * 512;
    const int e0   = blockIdx.y * 64;
    const int wave = tid >> 6;
    const int lane = tid & 63;
    const int l32  = lane & 31;
    const int hi   = lane >> 5;
    const int wt0  = wave * 128;

    if (tid < 64)       swb[tid] = sw[e0 + tid];
    else if (tid < 128) swb[tid] = bias[e0 + tid - 64];

    f32x16 acc[2][4];
    #pragma unroll
    for (int es = 0; es < 2; ++es)
        #pragma unroll
        for (int ts = 0; ts < 4; ++ts) acc[es][ts] = (f32x16)0.f;

    const unsigned short* xbase = xT + ((size_t)b * XROWS + tb) * E_;
    const int cw = wave * CPW;               // this wave's first chunk

    // per-lane global source for chunk g at i-offset i0 (slot2 = pad, dummy src)
    auto src = [&](int g, int i0) -> const unsigned short* {
        if (g < XCH) {
            int row = g / 3, slot = g - row * 3;
            return xbase + (size_t)row * E_ + i0 + (slot < 2 ? slot * 8 : 0);
        } else {
            int wg = g - XCH;
            int rowl = wg / 3, slot = wg - rowl * 3;
            int k = rowl >> 6, ep = rowl & 63;
            return Wtb + ((size_t)(k * E_ + e0 + ep) * E_ + i0 + (slot < 2 ? slot * 8 : 0));
        }
    };
    // issue this wave's 10 DMA loads for step at i-offset i0 into buffer p
    auto stage = [&](int p, int i0) {
        unsigned short* base = &SB[p][0];
        #pragma unroll
        for (int it = 0; it < 9; ++it) {
            int g = cw + it * 64;
            gload16(src(g + lane, i0), base + (size_t)g * 8);
        }
        {
            int g = cw + 576;
            if (lane < CPW - 576)
                gload16(src(g + lane, i0), base + (size_t)g * 8);
        }
    };

    stage(0, 0);
    int p = 0;
    for (int s = 0; s < 32; ++s) {
        if (s + 1 < 32) {
            stage(p ^ 1, (s + 1) * 16);
            asm volatile("s_waitcnt vmcnt(10)" ::: "memory");
        } else {
            asm volatile("s_waitcnt vmcnt(0)" ::: "memory");
        }
        asm volatile("" ::: "memory");
        __builtin_amdgcn_s_barrier();        // buf[p] ready for all waves
        asm volatile("" ::: "memory");

        const unsigned short* Xb = &SB[p][0];
        const unsigned short* Wb = &SB[p][WOFF];
        #pragma unroll
        for (int k = 0; k < K_; ++k) {
            s16x8 a0 = *(const s16x8*)(Wb + (size_t)(k * 64 + l32) * PITCH + hi * 8);
            s16x8 a1 = *(const s16x8*)(Wb + (size_t)(k * 64 + 32 + l32) * PITCH + hi * 8);
            #pragma unroll
            for (int ts = 0; ts < 4; ++ts) {
                s16x8 bv = *(const s16x8*)(Xb + (size_t)(wt0 + ts * 32 + l32 + k) * PITCH + hi * 8);
                acc[0][ts] = __builtin_amdgcn_mfma_f32_32x32x16_bf16(a0, bv, acc[0][ts], 0, 0, 0);
                acc[1][ts] = __builtin_amdgcn_mfma_f32_32x32x16_bf16(a1, bv, acc[1][ts], 0, 0, 0);
            }
        }

        asm volatile("" ::: "memory");
        __builtin_amdgcn_s_barrier();        // all waves done reading buf[p]
        asm volatile("" ::: "memory");
        p ^= 1;
    }

    // Epilogue: bias add, yP store (bf16, +8 pad offset), fused z partial.
    // C/D layout (32x32): col(t)=lane&31, row(e)=(reg&3)+8*(reg>>2)+4*hi
    #pragma unroll
    for (int ts = 0; ts < 4; ++ts) {
        const int t = tb + wt0 + ts * 32 + l32;
        const bool tv = (t < LC);
        float zp = 0.f;
        #pragma unroll
        for (int es = 0; es < 2; ++es) {
            #pragma unroll
            for (int reg = 0; reg < 16; ++reg) {
                int er = es * 32 + (reg & 3) + 8 * (reg >> 2) + 4 * hi;
                float v = acc[es][ts][reg] + swb[64 + er];
                if (tv) yP[((size_t)(b * E_ + e0 + er)) * LCP + 8 + t] = f2bf(v);
                zp += swb[er] * v;
            }
        }
        zp += __shfl_xor(zp, 32);
        if (hi == 0 && tv) atomicAdd(&zP[(size_t)b * LCP + 8 + t], zp);
    }
}

// ---------------------------------------------------------------------------
// Kernel 4: blend widths 1..3 + 2x downsample (round-5 out3, unchanged).
// ---------------------------------------------------------------------------
__global__ __launch_bounds__(256) void out3_kernel(const unsigned short* __restrict__ yP,
                                                   const float* __restrict__ zP,
                                                   float* __restrict__ out) {
    __shared__ float  zsL[1040];
    __shared__ float2 attA[512];
    __shared__ float2 attB[512];
    __shared__ float  attC[512];
    const int bx  = blockIdx.x;               // b*64 + eg
    const int b   = bx >> 6;
    const int eg  = bx & 63;
    const int d0  = blockIdx.y << 9;
    const int tid = threadIdx.x;

    const float* zbase = zP + (size_t)b * LCP + 2 * d0;
    for (int c = tid; c < 260; c += 256)
        *(f32x4*)&zsL[c * 4] = *(const f32x4*)(zbase + c * 4);
    __syncthreads();

    for (int dl = tid; dl < 512; dl += 256) {
        int lt = 2 * dl + 6;
        float z0 = zsL[lt + 0], z1 = zsL[lt + 1], z2 = zsL[lt + 2];
        float z3 = zsL[lt + 3], z4 = zsL[lt + 4], z5 = zsL[lt + 5];
        unsigned t  = 2u * (unsigned)(d0 + dl);
        unsigned r3 = t % 3u;
        float a12 = z1 + z2, a34 = z3 + z4;
        float s0 = z0 + a12, s1 = a12 + z3, s2 = z2 + a34, s3 = a34 + z5;
        float S1a = z2, S1b = z3;
        float S2  = 0.5f * (z2 + z3);
        float S3a = ((r3 == 0u) ? s2 : ((r3 == 1u) ? s1 : s0)) * (1.f / 3.f);
        float S3b = ((r3 == 0u) ? s2 : ((r3 == 1u) ? s1 : s3)) * (1.f / 3.f);
        float m0 = fmaxf(S1a, fmaxf(S2, S3a));
        float e1 = __expf(S1a - m0), e2 = __expf(S2 - m0), e3 = __expf(S3a - m0);
        float r0 = 1.f / (e1 + e2 + e3);
        float m1 = fmaxf(S1b, fmaxf(S2, S3b));
        float f1 = __expf(S1b - m1), f2 = __expf(S2 - m1), f3 = __expf(S3b - m1);
        float r1 = 1.f / (f1 + f2 + f3);
        attA[dl] = make_float2(0.5f * e1 * r0, 0.5f * f1 * r1);
        attB[dl] = make_float2(0.25f * (e2 * r0 + f2 * r1), (0.5f / 3.f) * e3 * r0);
        attC[dl] = (0.5f / 3.f) * f3 * r1;
    }
    __syncthreads();

    const int e    = tid >> 5;
    const int l32b = tid & 31;
    const unsigned short* yrow = yP + ((size_t)(b * E_ + eg * 8 + e)) * LCP + 2 * d0;
    float* orow = out + ((size_t)(b * E_ + eg * 8 + e)) * LOUT + d0;
    #pragma unroll
    for (int ii = 0; ii < 16; ++ii) {
        int dl = l32b + 32 * ii;
        unsigned u0 = *(const unsigned*)(yrow + 2 * dl + 6);
        unsigned u1 = *(const unsigned*)(yrow + 2 * dl + 8);
        unsigned u2 = *(const unsigned*)(yrow + 2 * dl + 10);
        float v0 = bflo(u0), v1 = bfhi(u0);
        float v2 = bflo(u1), v3 = bfhi(u1);
        float v4 = bflo(u2), v5 = bfhi(u2);
        unsigned t  = 2u * (unsigned)(d0 + dl);
        unsigned r3 = t % 3u;
        float a12 = v1 + v2, a34 = v3 + v4;
        float s0 = v0 + a12, s1 = a12 + v3, s2 = v2 + a34, s3 = a34 + v5;
        float C3a = (r3 == 0u) ? s2 : ((r3 == 1u) ? s1 : s0);
        float C3b = (r3 == 0u) ? s2 : ((r3 == 1u) ? s1 : s3);
        float2 wA = attA[dl];
        float2 wB = attB[dl];
        float  wC = attC[dl];
        float o = wA.x * v2 + wA.y * v3 + wB.x * (v2 + v3) + wB.y * C3a + wC * C3b;
        orow[dl] = o;
    }
}

// ---------------------------------------------------------------------------
extern "C" void kernel_launch(void* const* d_in, const int* in_sizes, int n_in,
                              void* d_out, int out_size, void* d_ws, size_t ws_size,
                              hipStream_t stream) {
    const float* x       = (const float*)d_in[0];
    const float* conv_w  = (const float*)d_in[1];
    const float* conv_b  = (const float*)d_in[2];
    const float* score_w = (const float*)d_in[3];
    float* out = (float*)d_out;

    // workspace (ushort units): Wtb[5*512*512] | xT[B*XROWS*E] | yP[B*E*LCP] | zP fp32[B*LCP]
    unsigned short* base = (unsigned short*)d_ws;
    unsigned short* Wtb = base;
    unsigned short* xT  = Wtb + (size_t)K_ * E_ * E_;            // 1,310,720
    unsigned short* yP  = xT + (size_t)B_ * XROWS * E_;          // +33,587,200
    float*          zP  = (float*)(yP + (size_t)B_ * E_ * LCP);  // +33,619,968

    wt_kernel<<<dim3((E_ * E_ * K_ + 255) / 256), 256, 0, stream>>>(conv_w, Wtb);
    xt_kernel<<<dim3(L_ / 64, E_ / 64, B_), 256, 0, stream>>>(x, xT);
    zero_aux<<<dim3((B_ * LCP + B_ * E_ * 20 + 255) / 256), 256, 0, stream>>>(yP, zP);
    conv_mfma<<<dim3(B_ * 16, E_ / 64), 256, 0, stream>>>(xT, Wtb, conv_b, score_w, yP, zP);
    out3_kernel<<<dim3(B_ * 64, LOUT / 512), 256, 0, stream>>>(yP, zP, out);
}

// Round 7
// 402.368 us; speedup vs baseline: 1.0643x; 1.0643x over previous
//
#include <hip/hip_runtime.h>
#include <math.h>

// Problem constants
#define B_    8
#define E_    512
#define L_    8192
#define K_    5
#define LC    8188      // L - K + 1
#define LOUT  4096      // L / DS
#define XROWS 8200      // xT t-rows: 8192 data + 8 slack rows
#define LCP   8208      // padded y/z row length: [0,8) front zeros, data at 8+t, back zeros

// Workspace total 137,298,432 B (under round-0 proven 137,592,704 B)

typedef float  f32x4   __attribute__((ext_vector_type(4)));
typedef float  f32x16  __attribute__((ext_vector_type(16)));
typedef short  s16x4   __attribute__((ext_vector_type(4)));
typedef short  s16x8   __attribute__((ext_vector_type(8)));

__device__ __forceinline__ unsigned short f2bf(float f) {
    union { float f; unsigned u; } v; v.f = f;
    unsigned r = v.u + 0x7FFFu + ((v.u >> 16) & 1u);
    return (unsigned short)(r >> 16);
}
__device__ __forceinline__ float bflo(unsigned u) {
    union { unsigned u; float f; } v; v.u = u << 16; return v.f;
}
__device__ __forceinline__ float bfhi(unsigned u) {
    union { unsigned u; float f; } v; v.u = u & 0xFFFF0000u; return v.f;
}

// ---------------------------------------------------------------------------
// Kernel 0: prep = weight pack [e][i][k] fp32 -> Wtb[k][e][i] bf16
//           + zP zeroing + yP edge-pad zeroing (merged, independent writes)
// ---------------------------------------------------------------------------
__global__ __launch_bounds__(256) void prep_kernel(const float* __restrict__ w,
                                                   unsigned short* __restrict__ Wtb,
                                                   unsigned short* __restrict__ yP,
                                                   float* __restrict__ zP) {
    int idx = blockIdx.x * 256 + threadIdx.x;
    if (idx < E_ * E_ * K_) {
        int i    = idx & (E_ - 1);
        int rest = idx >> 9;            // k*E + e
        int e    = rest & (E_ - 1);
        int k    = rest >> 9;
        Wtb[idx] = f2bf(w[((size_t)e * E_ + i) * K_ + k]);
    }
    if (idx < B_ * LCP) zP[idx] = 0.f;
    if (idx < B_ * E_ * 20) {
        int row = idx / 20, j = idx - row * 20;
        int col = (j < 8) ? j : (8 + LC + (j - 8));   // front 8 + back 12 pads
        yP[(size_t)row * LCP + col] = 0;
    }
}

// ---------------------------------------------------------------------------
// Kernel 1: transpose x[b][i][t] fp32 -> xT[b][t][i] bf16 (f32x4 loads)
// ---------------------------------------------------------------------------
__global__ __launch_bounds__(256) void xt_kernel(const float* __restrict__ x,
                                                 unsigned short* __restrict__ xT) {
    __shared__ float s[64][65];
    const int b  = blockIdx.z;
    const int i0 = blockIdx.y * 64;
    const int t0 = blockIdx.x * 64;
    #pragma unroll
    for (int j = 0; j < 4; ++j) {
        int idx = threadIdx.x + j * 256;
        int r = idx >> 4, c4 = idx & 15;
        f32x4 v = *(const f32x4*)(x + ((size_t)b * E_ + i0 + r) * L_ + t0 + c4 * 4);
        s[c4 * 4 + 0][r] = v[0];
        s[c4 * 4 + 1][r] = v[1];
        s[c4 * 4 + 2][r] = v[2];
        s[c4 * 4 + 3][r] = v[3];
    }
    __syncthreads();
    #pragma unroll
    for (int j = 0; j < 4; ++j) {
        int idx = threadIdx.x + j * 256;
        int tt = idx >> 4, ig = (idx & 15) * 4;
        s16x4 v;
        v[0] = (short)f2bf(s[tt][ig + 0]);
        v[1] = (short)f2bf(s[tt][ig + 1]);
        v[2] = (short)f2bf(s[tt][ig + 2]);
        v[3] = (short)f2bf(s[tt][ig + 3]);
        *(s16x4*)&xT[((size_t)b * XROWS + t0 + tt) * E_ + i0 + ig] = v;
    }
}

// ---------------------------------------------------------------------------
// Kernel 3: implicit-GEMM conv via 32x32x16 bf16 MFMA + fused z-score.
// ROUND-3 VERSION (proven 180 us): block 64e x 512t, 4 waves, wave 64e x 128t.
// ---------------------------------------------------------------------------
__global__ __launch_bounds__(256, 2) void conv_mfma(const unsigned short* __restrict__ xT,
                                                    const unsigned short* __restrict__ Wtb,
                                                    const float* __restrict__ bias,
                                                    const float* __restrict__ sw,
                                                    unsigned short* __restrict__ yP,
                                                    float* __restrict__ zP) {
    __shared__ unsigned short Xs[520][40];   // rows padded to 80 B
    __shared__ unsigned short Ws[K_][64][40];
    __shared__ float swb[128];               // [0:64) = score_w, [64:128) = bias

    const int tid  = threadIdx.x;
    const int nt   = blockIdx.x;
    const int b    = nt >> 4;
    const int tb   = (nt & 15) * 512;
    const int e0   = blockIdx.y * 64;
    const int wave = tid >> 6;
    const int lane = tid & 63;
    const int l32  = lane & 31;
    const int hi   = lane >> 5;
    const int wt0  = wave * 128;

    if (tid < 64)       swb[tid] = sw[e0 + tid];
    else if (tid < 128) swb[tid] = bias[e0 + tid - 64];

    f32x16 acc[2][4];
    #pragma unroll
    for (int es = 0; es < 2; ++es)
        #pragma unroll
        for (int ts = 0; ts < 4; ++ts) acc[es][ts] = (f32x16)0.f;

    const unsigned short* xbase = xT + ((size_t)b * XROWS + tb) * E_;

    s16x8 xpf[9];
    s16x8 wpf[5];

    auto load_tile = [&](int i0) {
        #pragma unroll
        for (int j = 0; j < 8; ++j) {
            int idx = tid + j * 256;
            int r = idx >> 2, c = idx & 3;
            xpf[j] = *(const s16x8*)(xbase + (size_t)r * E_ + i0 + c * 8);
        }
        {
            int idx = tid + 2048;
            if (idx < 2080) {
                int r = idx >> 2, c = idx & 3;
                xpf[8] = *(const s16x8*)(xbase + (size_t)r * E_ + i0 + c * 8);
            }
        }
        #pragma unroll
        for (int j = 0; j < 5; ++j) {
            int idx = tid + j * 256;
            int rl = idx >> 2, c = idx & 3;
            int k = rl >> 6, ep = rl & 63;
            wpf[j] = *(const s16x8*)(Wtb + ((size_t)(k * E_ + e0 + ep) * E_ + i0 + c * 8));
        }
    };
    auto store_tile = [&]() {
        #pragma unroll
        for (int j = 0; j < 8; ++j) {
            int idx = tid + j * 256;
            int r = idx >> 2, c = idx & 3;
            *(s16x8*)&Xs[r][c * 8] = xpf[j];
        }
        {
            int idx = tid + 2048;
            if (idx < 2080) {
                int r = idx >> 2, c = idx & 3;
                *(s16x8*)&Xs[r][c * 8] = xpf[8];
            }
        }
        #pragma unroll
        for (int j = 0; j < 5; ++j) {
            int idx = tid + j * 256;
            int rl = idx >> 2, c = idx & 3;
            int k = rl >> 6, ep = rl & 63;
            *(s16x8*)&Ws[k][ep][c * 8] = wpf[j];
        }
    };

    load_tile(0);
    for (int i0 = 0; i0 < E_; i0 += 32) {
        __syncthreads();            // previous compute done reading LDS
        store_tile();
        __syncthreads();
        if (i0 + 32 < E_) load_tile(i0 + 32);   // latency hidden under MFMAs

        #pragma unroll
        for (int k = 0; k < K_; ++k) {
            #pragma unroll
            for (int kk = 0; kk < 2; ++kk) {
                const int co = kk * 16 + hi * 8;
                s16x8 a0 = *(const s16x8*)&Ws[k][l32][co];
                s16x8 a1 = *(const s16x8*)&Ws[k][32 + l32][co];
                #pragma unroll
                for (int ts = 0; ts < 4; ++ts) {
                    s16x8 bv = *(const s16x8*)&Xs[wt0 + ts * 32 + l32 + k][co];
                    acc[0][ts] = __builtin_amdgcn_mfma_f32_32x32x16_bf16(a0, bv, acc[0][ts], 0, 0, 0);
                    acc[1][ts] = __builtin_amdgcn_mfma_f32_32x32x16_bf16(a1, bv, acc[1][ts], 0, 0, 0);
                }
            }
        }
    }

    // Epilogue: bias add, yP store (bf16, +8 pad offset), fused z partial.
    // C/D layout (32x32): col(t)=lane&31, row(e)=(reg&3)+8*(reg>>2)+4*hi
    #pragma unroll
    for (int ts = 0; ts < 4; ++ts) {
        const int t = tb + wt0 + ts * 32 + l32;
        const bool tv = (t < LC);
        float zp = 0.f;
        #pragma unroll
        for (int es = 0; es < 2; ++es) {
            #pragma unroll
            for (int reg = 0; reg < 16; ++reg) {
                int er = es * 32 + (reg & 3) + 8 * (reg >> 2) + 4 * hi;
                float v = acc[es][ts][reg] + swb[64 + er];
                if (tv) yP[((size_t)(b * E_ + e0 + er)) * LCP + 8 + t] = f2bf(v);
                zp += swb[er] * v;
            }
        }
        zp += __shfl_xor(zp, 32);
        if (hi == 0 && tv) atomicAdd(&zP[(size_t)b * LCP + 8 + t], zp);
    }
}

// ---------------------------------------------------------------------------
// Kernel 4: blend widths 1..3 + 2x downsample (round-5 out3, unchanged).
// ---------------------------------------------------------------------------
__global__ __launch_bounds__(256) void out3_kernel(const unsigned short* __restrict__ yP,
                                                   const float* __restrict__ zP,
                                                   float* __restrict__ out) {
    __shared__ float  zsL[1040];
    __shared__ float2 attA[512];
    __shared__ float2 attB[512];
    __shared__ float  attC[512];
    const int bx  = blockIdx.x;               // b*64 + eg
    const int b   = bx >> 6;
    const int eg  = bx & 63;
    const int d0  = blockIdx.y << 9;
    const int tid = threadIdx.x;

    const float* zbase = zP + (size_t)b * LCP + 2 * d0;
    for (int c = tid; c < 260; c += 256)
        *(f32x4*)&zsL[c * 4] = *(const f32x4*)(zbase + c * 4);
    __syncthreads();

    for (int dl = tid; dl < 512; dl += 256) {
        int lt = 2 * dl + 6;
        float z0 = zsL[lt + 0], z1 = zsL[lt + 1], z2 = zsL[lt + 2];
        float z3 = zsL[lt + 3], z4 = zsL[lt + 4], z5 = zsL[lt + 5];
        unsigned t  = 2u * (unsigned)(d0 + dl);
        unsigned r3 = t % 3u;
        float a12 = z1 + z2, a34 = z3 + z4;
        float s0 = z0 + a12, s1 = a12 + z3, s2 = z2 + a34, s3 = a34 + z5;
        float S1a = z2, S1b = z3;
        float S2  = 0.5f * (z2 + z3);
        float S3a = ((r3 == 0u) ? s2 : ((r3 == 1u) ? s1 : s0)) * (1.f / 3.f);
        float S3b = ((r3 == 0u) ? s2 : ((r3 == 1u) ? s1 : s3)) * (1.f / 3.f);
        float m0 = fmaxf(S1a, fmaxf(S2, S3a));
        float e1 = __expf(S1a - m0), e2 = __expf(S2 - m0), e3 = __expf(S3a - m0);
        float r0 = 1.f / (e1 + e2 + e3);
        float m1 = fmaxf(S1b, fmaxf(S2, S3b));
        float f1 = __expf(S1b - m1), f2 = __expf(S2 - m1), f3 = __expf(S3b - m1);
        float r1 = 1.f / (f1 + f2 + f3);
        attA[dl] = make_float2(0.5f * e1 * r0, 0.5f * f1 * r1);
        attB[dl] = make_float2(0.25f * (e2 * r0 + f2 * r1), (0.5f / 3.f) * e3 * r0);
        attC[dl] = (0.5f / 3.f) * f3 * r1;
    }
    __syncthreads();

    const int e    = tid >> 5;
    const int l32b = tid & 31;
    const unsigned short* yrow = yP + ((size_t)(b * E_ + eg * 8 + e)) * LCP + 2 * d0;
    float* orow = out + ((size_t)(b * E_ + eg * 8 + e)) * LOUT + d0;
    #pragma unroll
    for (int ii = 0; ii < 16; ++ii) {
        int dl = l32b + 32 * ii;
        unsigned u0 = *(const unsigned*)(yrow + 2 * dl + 6);
        unsigned u1 = *(const unsigned*)(yrow + 2 * dl + 8);
        unsigned u2 = *(const unsigned*)(yrow + 2 * dl + 10);
        float v0 = bflo(u0), v1 = bfhi(u0);
        float v2 = bflo(u1), v3 = bfhi(u1);
        float v4 = bflo(u2), v5 = bfhi(u2);
        unsigned t  = 2u * (unsigned)(d0 + dl);
        unsigned r3 = t % 3u;
        float a12 = v1 + v2, a34 = v3 + v4;
        float s0 = v0 + a12, s1 = a12 + v3, s2 = v2 + a34, s3 = a34 + v5;
        float C3a = (r3 == 0u) ? s2 : ((r3 == 1u) ? s1 : s0);
        float C3b = (r3 == 0u) ? s2 : ((r3 == 1u) ? s1 : s3);
        float2 wA = attA[dl];
        float2 wB = attB[dl];
        float  wC = attC[dl];
        float o = wA.x * v2 + wA.y * v3 + wB.x * (v2 + v3) + wB.y * C3a + wC * C3b;
        orow[dl] = o;
    }
}

// ---------------------------------------------------------------------------
extern "C" void kernel_launch(void* const* d_in, const int* in_sizes, int n_in,
                              void* d_out, int out_size, void* d_ws, size_t ws_size,
                              hipStream_t stream) {
    const float* x       = (const float*)d_in[0];
    const float* conv_w  = (const float*)d_in[1];
    const float* conv_b  = (const float*)d_in[2];
    const float* score_w = (const float*)d_in[3];
    float* out = (float*)d_out;

    // workspace (ushort units): Wtb[5*512*512] | xT[B*XROWS*E] | yP[B*E*LCP] | zP fp32[B*LCP]
    unsigned short* base = (unsigned short*)d_ws;
    unsigned short* Wtb = base;
    unsigned short* xT  = Wtb + (size_t)K_ * E_ * E_;            // 1,310,720
    unsigned short* yP  = xT + (size_t)B_ * XROWS * E_;          // +33,587,200
    float*          zP  = (float*)(yP + (size_t)B_ * E_ * LCP);  // +33,619,968

    prep_kernel<<<dim3((E_ * E_ * K_ + 255) / 256), 256, 0, stream>>>(conv_w, Wtb, yP, zP);
    xt_kernel<<<dim3(L_ / 64, E_ / 64, B_), 256, 0, stream>>>(x, xT);
    conv_mfma<<<dim3(B_ * 16, E_ / 64), 256, 0, stream>>>(xT, Wtb, conv_b, score_w, yP, zP);
    out3_kernel<<<dim3(B_ * 64, LOUT / 512), 256, 0, stream>>>(yP, zP, out);
}